// Round 2
// baseline (134.747 us; speedup 1.0000x reference)
//
#include <hip/hip_runtime.h>

// Problem constants (from reference)
#define BB   4
#define N1   1024
#define DIM  1024
#define FF   4
#define NN   1025           // N1 + 1
#define NTOT (FF * NN)      // 4100
#define SIM_TOTAL ((size_t)BB * N1 * NTOT)   // 16,793,600 floats (divisible by 4)
#define NEGV (-1e9f)

// ---------------------------------------------------------------------------
// Kernel 1: pure streaming fill of the sim region with -1e9.
// Store-only, float4, grid-stride. Measured device fill rate ~6.5 TB/s.
// ---------------------------------------------------------------------------
__global__ __launch_bounds__(256)
void fill_kernel(float4* __restrict__ out4, int total4) {
    const float4 negv = make_float4(NEGV, NEGV, NEGV, NEGV);
    const int stride = gridDim.x * 256;
    for (int k = blockIdx.x * 256 + threadIdx.x; k < total4; k += stride)
        out4[k] = negv;
}

// ---------------------------------------------------------------------------
// Kernel 2: one WAVE (64 lanes) per output row (b, i). No LDS, no barriers.
//   lane loads 4 float4 of lhs row + 4x4 float4 of the 4 rhs rows (20 loads
//   in flight), accumulates |l|^2, dot_f, |r_f|^2, butterfly-reduces 9
//   scalars across the wave, lane 0 writes 4 kept sims + lhs_norm.
// Runs AFTER fill_kernel (same stream) so its scatter overwrites the fill.
// ---------------------------------------------------------------------------
__global__ __launch_bounds__(256)
void dot_kernel(const float* __restrict__ lhs,
                const float* __restrict__ rhs,
                float* __restrict__ out) {
    const int row  = blockIdx.x * 4 + (threadIdx.x >> 6);  // 0 .. B*N1-1
    const int lane = threadIdx.x & 63;
    const int b    = row >> 10;          // / N1
    const int i    = row & (N1 - 1);     // % N1

    // ---- lhs row: 1024 floats = 256 float4; lane handles lane+64k ----
    const float4* lrow = (const float4*)(lhs + (size_t)row * DIM);
    float4 lv[4];
#pragma unroll
    for (int k = 0; k < 4; ++k)
        lv[k] = lrow[lane + 64 * k];

    float l2 = 0.f;
#pragma unroll
    for (int k = 0; k < 4; ++k)
        l2 += lv[k].x * lv[k].x + lv[k].y * lv[k].y +
              lv[k].z * lv[k].z + lv[k].w * lv[k].w;

    // ---- 4 rhs rows: f*NN + i + 1 ----
    float dotf[FF], r2f[FF];
#pragma unroll
    for (int f = 0; f < FF; ++f) {
        const size_t rrow_idx = (size_t)b * NTOT + (size_t)f * NN + (i + 1);
        const float4* rrow = (const float4*)(rhs + rrow_idx * DIM);
        float d = 0.f, r2 = 0.f;
#pragma unroll
        for (int k = 0; k < 4; ++k) {
            const float4 rv = rrow[lane + 64 * k];
            d  += lv[k].x * rv.x + lv[k].y * rv.y + lv[k].z * rv.z + lv[k].w * rv.w;
            r2 += rv.x * rv.x + rv.y * rv.y + rv.z * rv.z + rv.w * rv.w;
        }
        dotf[f] = d;
        r2f[f]  = r2;
    }

    // ---- butterfly reduce 9 scalars across the 64-lane wave ----
    float vals[9];
    vals[0] = l2;
#pragma unroll
    for (int f = 0; f < FF; ++f) {
        vals[1 + 2 * f] = dotf[f];
        vals[2 + 2 * f] = r2f[f];
    }
#pragma unroll
    for (int q = 0; q < 9; ++q) {
#pragma unroll
        for (int off = 1; off < 64; off <<= 1)
            vals[q] += __shfl_xor(vals[q], off, 64);
    }

    if (lane == 0) {
        const float L2 = vals[0];
        float* orow = out + (size_t)row * NTOT;
#pragma unroll
        for (int f = 0; f < FF; ++f) {
            const float d  = vals[1 + 2 * f];
            const float r2 = vals[2 + 2 * f];
            orow[f * NN + i + 1] = (d * d) / (L2 * r2);
        }
        out[SIM_TOTAL + row] = sqrtf(L2);   // lhs_norm (B, N1, 1)
    }
}

extern "C" void kernel_launch(void* const* d_in, const int* in_sizes, int n_in,
                              void* d_out, int out_size, void* d_ws, size_t ws_size,
                              hipStream_t stream) {
    const float* lhs = (const float*)d_in[0];  // (B, N1, DIM)
    const float* rhs = (const float*)d_in[1];  // (B, NTOT, DIM)
    float* out = (float*)d_out;                // sim (B,N1,NTOT) ++ lhs_norm (B,N1,1)

    const int total4 = (int)(SIM_TOTAL / 4);   // 4,198,400 float4
    fill_kernel<<<2048, 256, 0, stream>>>((float4*)out, total4);
    dot_kernel<<<(BB * N1) / 4, 256, 0, stream>>>(lhs, rhs, out);
}